// Round 1
// 255.843 us; speedup vs baseline: 1.3048x; 1.3048x over previous
//
#include <hip/hip_runtime.h>

// CIR Euler-Maruyama scan, B=16384 rows x S=2048 steps.
// One wave (64 threads) per block, lane = batch row, grid=256 (~1 wave/CU).
//
// R2 theory: kernel is LATENCY-bound (occupancy 2.8% is problem-capped at
// 256 waves; scan serial in S). VALUBusy 13% => ~87% exposed stalls from
// (a) the store phase running AFTER each tile's compute instead of inside
// its dependency bubbles, (b) libm sqrtf's fixup sequence on the chain.
//
// Changes vs R1:
//  - Double-buffered LDS output tile; store of tile t-1 fused into the
//    compute loop of tile t (single wave -> no barrier; lgkmcnt orders).
//  - OSTRIDE 65 -> 68: column reads become aligned ds_read_b128 (4x fewer
//    LDS ops). Writes (4j+lane)%32 = 2-way (free); b128 reads: lanes 0..7
//    hit banks 4(lane+i)%32 = all 32 banks -> conflict-free.
//  - Chain refactor: v' = fma(c*w, sqrt(max(v,0)), fma(1-kdt, v, kdt*mu~)),
//    c = sigma*sqrt(DT) precomputed. Critical path max->sqrt->fma; drift
//    fma + output blend off-chain. Raw v_sqrt_f32 via builtin.

#define B_ROWS   16384
#define SEQ      2048
#define L_X      64
#define V_LAST   0.04f
#define DT_C     (1.0f / 2048.0f)
#define PROB     0.5f

#define TILE     64
#define NT       (SEQ / TILE)     // 32 tiles
#define CHT      (TILE / 4)       // 16 float4 chunks per tile per lane
#define OSTRIDE  68               // [col][row], pad to 68 words (16B-aligned cols)

__device__ __forceinline__ float cir_step(float v, float c, float a1, float b1) {
    // v' = c*sqrt(max(v,0)) + (a1*v + b1);  a1 = 1-kappa*DT, b1 = kappa*DT*tol_mu
    float s = __builtin_amdgcn_sqrtf(fmaxf(v, 0.0f));
    return fmaf(c, s, fmaf(a1, v, b1));
}

__global__ __launch_bounds__(64) void cir_scan_kernel(
    const float* __restrict__ x,      // (B, 64, 1)
    const float* __restrict__ W,      // (B, S)
    const float* __restrict__ kappa_p,
    const float* __restrict__ mu_p,
    const float* __restrict__ sigma_p,
    float* __restrict__ out)          // (B, S)
{
    __shared__ __align__(16) float o_lds[2][TILE * OSTRIDE];   // 2 x 17.4 KB

    const int lane = threadIdx.x;              // 0..63, owns batch row row0+lane
    const int row0 = blockIdx.x * 64;
    const int row  = row0 + lane;

    // ---- xmean over 64 samples (256B contiguous per lane) ----
    const float4* xr = reinterpret_cast<const float4*>(x + (size_t)row * L_X);
    float sum = 0.0f;
#pragma unroll
    for (int i = 0; i < L_X / 4; ++i) {
        float4 t = xr[i];
        sum += (t.x + t.y) + (t.z + t.w);
    }
    const float xmean = sum * (1.0f / 64.0f);

    const float kappa = kappa_p[0];
    const float mu    = mu_p[0];
    const float sigma = sigma_p[0];

    const float tol_mu = mu + xmean;
    const float kdt    = kappa * DT_C;
    const float a1     = 1.0f - kdt;
    const float b1     = kdt * tol_mu;
    const float csd    = sigma * sqrtf(DT_C);  // sqrt(DT) folded into diffusion coeff
    const float hx     = (1.0f - PROB) * xmean;

    const float4* Wr = reinterpret_cast<const float4*>(W + (size_t)row * SEQ);

    // ---- prime: tile 0's 16 chunks into the register ring ----
    float4 buf[CHT];
#pragma unroll
    for (int i = 0; i < CHT; ++i) buf[i] = Wr[i];

    float v = V_LAST;
    float* cur = &o_lds[0][0];
    float* prv = &o_lds[1][0];

    // ---- tile 0: compute only; prefetch tile 1 ----
#pragma unroll
    for (int i = 0; i < CHT; ++i) {
        float4 w4 = buf[i];
        buf[i] = Wr[CHT + i];
        const int j = 4 * i;
        v = cir_step(v, csd * w4.x, a1, b1); cur[(j + 0) * OSTRIDE + lane] = fmaf(PROB, v, hx);
        v = cir_step(v, csd * w4.y, a1, b1); cur[(j + 1) * OSTRIDE + lane] = fmaf(PROB, v, hx);
        v = cir_step(v, csd * w4.z, a1, b1); cur[(j + 2) * OSTRIDE + lane] = fmaf(PROB, v, hx);
        v = cir_step(v, csd * w4.w, a1, b1); cur[(j + 3) * OSTRIDE + lane] = fmaf(PROB, v, hx);
    }

    // ---- main: compute tile t into cur while streaming tile t-1 from prv ----
    for (int t = 1; t < NT; ++t) {
        float* tmp = cur; cur = prv; prv = tmp;
        const size_t obP = (size_t)row0 * SEQ + (size_t)(t - 1) * TILE;
        const bool  more = (t + 1 < NT);
        const int   nb   = (t + 1) * CHT;
#pragma unroll
        for (int i = 0; i < CHT; ++i) {
            float4 w4 = buf[i];
            if (more) buf[i] = Wr[nb + i];     // prefetch next tile's chunk
            const int j = 4 * i;

            // stream 4 rows of tile t-1: one b128 LDS read (col = lane),
            // 4 coalesced 256B stores -- issues into the compute chain's bubbles
            float4 a4 = *reinterpret_cast<const float4*>(prv + lane * OSTRIDE + j);
            out[obP + (size_t)(j + 0) * SEQ + lane] = a4.x;
            out[obP + (size_t)(j + 1) * SEQ + lane] = a4.y;
            out[obP + (size_t)(j + 2) * SEQ + lane] = a4.z;
            out[obP + (size_t)(j + 3) * SEQ + lane] = a4.w;

            v = cir_step(v, csd * w4.x, a1, b1); cur[(j + 0) * OSTRIDE + lane] = fmaf(PROB, v, hx);
            v = cir_step(v, csd * w4.y, a1, b1); cur[(j + 1) * OSTRIDE + lane] = fmaf(PROB, v, hx);
            v = cir_step(v, csd * w4.z, a1, b1); cur[(j + 2) * OSTRIDE + lane] = fmaf(PROB, v, hx);
            v = cir_step(v, csd * w4.w, a1, b1); cur[(j + 3) * OSTRIDE + lane] = fmaf(PROB, v, hx);
        }
    }

    // ---- epilogue: stream last tile from cur ----
    const size_t obL = (size_t)row0 * SEQ + (size_t)(NT - 1) * TILE;
#pragma unroll
    for (int i = 0; i < CHT; ++i) {
        const int j = 4 * i;
        float4 a4 = *reinterpret_cast<const float4*>(cur + lane * OSTRIDE + j);
        out[obL + (size_t)(j + 0) * SEQ + lane] = a4.x;
        out[obL + (size_t)(j + 1) * SEQ + lane] = a4.y;
        out[obL + (size_t)(j + 2) * SEQ + lane] = a4.z;
        out[obL + (size_t)(j + 3) * SEQ + lane] = a4.w;
    }
}

extern "C" void kernel_launch(void* const* d_in, const int* in_sizes, int n_in,
                              void* d_out, int out_size, void* d_ws, size_t ws_size,
                              hipStream_t stream) {
    const float* x     = (const float*)d_in[0];
    const float* W     = (const float*)d_in[1];
    const float* kappa = (const float*)d_in[2];
    const float* mu    = (const float*)d_in[3];
    const float* sigma = (const float*)d_in[4];
    float* out = (float*)d_out;

    dim3 grid(B_ROWS / 64);   // 256 blocks -> ~1 per CU
    dim3 block(64);           // exactly one wave
    hipLaunchKernelGGL(cir_scan_kernel, grid, block, 0, stream,
                       x, W, kappa, mu, sigma, out);
}